// Round 5
// baseline (153.349 us; speedup 1.0000x reference)
//
#include <hip/hip_runtime.h>

// MinibatchDiscrimination: B=512, IN=512, OUT=64, KD=8 (fp32 in/out)
// out[i, 0:512] = x[i, :]
// out[i, 512+o] = sum_j exp(-sum_k |M[i,o,k] - M[j,o,k]|),  M = x @ T
//
// R9: ONE kernel, NO cross-block sync (R8's fence/spin storm cost ~93us),
// redundant per-block recompute (R5 structure) but latency-engineered.
//  Cost model (R5/R8 evidence): total = 40.5us unconditional ws-poison fill
//  + ~9us launch/fixed + kernel. 2-kernel path is stuck at ~71 (2x10us
//  launches + 12us kernels). This kernel targets ~11us -> total ~60.
//  Block (o=bx>>2, ic=bx&3), 512 thr = 8 waves, grid 256 = 1 block/CU.
//  Floors: phase-1 redundant x-read 1MB/CU over CU<->L2 link ~7.5us;
//  phase-2 pairs 65536 pairs x 18 VALU / 128 lanes = 3.8us. Pipeline:
//  4 rounds; round r: MFMA-computes M-quarter (ic+r)&3 (8 waves x 16 rows,
//  full K=512); the pairs pass over quarter (ic+r-1)&3 is placed BETWEEN
//  the round's x-load issue and the pack+MFMA that consumes them -> pairs
//  VALU fills the L2 latency/BW stall. mi rows = quarter ic (round 0).
//  B-frags (T-slice) staged to LDS bf16 once, preloaded to 64 VGPR, reused
//  all rounds. M stored to LDS s[512][SROW=12] pre-scaled by log2e -> exp2.

#define B_    512
#define IN_   512
#define OUT_  64
#define ROW_  576
#define ROW4_ 144
#define SROW  12           // padded M-row stride in floats (48 B, 16B-aligned)
#define LOG2E 1.44269504088896340736f

typedef short short8 __attribute__((ext_vector_type(8)));
typedef float f32x4  __attribute__((ext_vector_type(4)));

__device__ __forceinline__ unsigned short f2bf(float f) {
    // round-half-up truncation to bf16; exp(-d) suppression makes the
    // 0.4% relative error invisible (non-self d ~ 200, self-term exact 0)
    return (unsigned short)((__float_as_uint(f) + 0x8000u) >> 16);
}
__device__ __forceinline__ unsigned pack_bf2(float lo, float hi) {
    unsigned a = (__float_as_uint(lo) + 0x8000u) >> 16;
    unsigned b = (__float_as_uint(hi) + 0x8000u) & 0xFFFF0000u;
    return a | b;
}

__global__ __launch_bounds__(512)
void fused_kernel(const float* __restrict__ x, const float* __restrict__ T,
                  float* __restrict__ out) {
    __shared__ __attribute__((aligned(16))) float s[B_ * SROW];   // 24 KB M-slice
    __shared__ unsigned short btT[8][520];                        // 8.1 KB T^T bf16
    __shared__ float s2[4][128];                                  // 2 KB partials

    int t  = threadIdx.x;
    int bx = blockIdx.x;
    int o  = bx >> 2;
    int ic = bx & 3;

    // side job: copy this block's 4KB share of x into out cols 0..511
    if (t < 256) {
        int v = bx * 256 + t;                     // [0, 65536) float4s of x
        ((float4*)out)[(v >> 7) * ROW4_ + (v & 127)] = ((const float4*)x)[v];
    }

    int lane = t & 63, w = t >> 6;                // 8 waves
    int r = lane & 15, q = lane >> 4;

    float4 fa[8], fb[8];                          // x prefetch regs (64 VGPR)

    // ---- round 0 load issue (quarter ic), first K-half ----
    const float* pa0 = x + (ic * 128 + w * 16 + r) * IN_ + q * 8;
    #pragma unroll
    for (int kt = 0; kt < 8; ++kt) {
        fa[kt] = *(const float4*)(pa0 + kt * 32);
        fb[kt] = *(const float4*)(pa0 + kt * 32 + 4);
    }

    // ---- stage T[:,o,:]^T as bf16: thread t handles k=t ----
    {
        const float* tp = T + t * (OUT_ * 8) + o * 8;
        float4 c0 = *(const float4*)tp;
        float4 c1 = *(const float4*)(tp + 4);
        btT[0][t] = f2bf(c0.x); btT[1][t] = f2bf(c0.y);
        btT[2][t] = f2bf(c0.z); btT[3][t] = f2bf(c0.w);
        btT[4][t] = f2bf(c1.x); btT[5][t] = f2bf(c1.y);
        btT[6][t] = f2bf(c1.z); btT[7][t] = f2bf(c1.w);
    }
    __syncthreads();

    // ---- preload all 16 B-frags once (reused every round; 64 VGPR) ----
    short8 Bv[16];
    {
        int rb = r & 7;                           // cols 8-15 duplicate kd 0-7;
        #pragma unroll                            // their C columns are discarded
        for (int kt = 0; kt < 16; ++kt)
            Bv[kt] = *(const short8*)&btT[rb][q * 8 + kt * 32];
    }

    auto mfma8 = [&](f32x4& ac, int kbase) {
        #pragma unroll
        for (int kt = 0; kt < 8; ++kt) {
            union { unsigned u[4]; short8 v; } A;
            A.u[0] = pack_bf2(fa[kt].x, fa[kt].y);
            A.u[1] = pack_bf2(fa[kt].z, fa[kt].w);
            A.u[2] = pack_bf2(fb[kt].x, fb[kt].y);
            A.u[3] = pack_bf2(fb[kt].z, fb[kt].w);
            ac = __builtin_amdgcn_mfma_f32_16x16x32_bf16(A.v, Bv[kt + kbase], ac, 0, 0, 0);
        }
    };
    auto load8 = [&](const float* pa, int kbase) {
        #pragma unroll
        for (int kt = 0; kt < 8; ++kt) {
            fa[kt] = *(const float4*)(pa + (kt + kbase) * 32);
            fb[kt] = *(const float4*)(pa + (kt + kbase) * 32 + 4);
        }
    };
    auto writeRows = [&](const f32x4& ac, int row0) {
        // C/D map: row = q*4+rr, col = r -> M row = row0+q*4+rr, kd = r (<8)
        if (r < 8) {
            #pragma unroll
            for (int rr = 0; rr < 4; ++rr)
                s[(row0 + q * 4 + rr) * SROW + r] = ac[rr] * LOG2E;
        }
    };

    // ---- round 0 compute (quarter ic): no pairs to overlap yet ----
    {
        f32x4 acc = {0.f, 0.f, 0.f, 0.f};
        mfma8(acc, 0);
        load8(pa0, 8);
        mfma8(acc, 8);
        writeRows(acc, ic * 128 + w * 16);
    }
    __syncthreads();

    // ---- mi: this thread's own M row (quarter ic, just computed) ----
    int il = t & 127, win = t >> 7;               // win wave-uniform (2 waves/win)
    float m0, m1, m2, m3, m4, m5, m6, m7;
    {
        const float* p = s + (ic * 128 + il) * SROW;
        float4 lo = *(const float4*)p;
        float4 hi = *(const float4*)(p + 4);
        m0 = lo.x; m1 = lo.y; m2 = lo.z; m3 = lo.w;
        m4 = hi.x; m5 = hi.y; m6 = hi.z; m7 = hi.w;
    }
    float accp = 0.f;

    auto pairs16 = [&](const float*& sj) {
        #pragma unroll
        for (int jj = 0; jj < 16; ++jj) {
            float4 vlo = *(const float4*)sj;       // wave-uniform -> broadcast
            float4 vhi = *(const float4*)(sj + 4);
            sj += SROW;
            float d = fabsf(m0 - vlo.x) + fabsf(m1 - vlo.y)
                    + fabsf(m2 - vlo.z) + fabsf(m3 - vlo.w)
                    + fabsf(m4 - vhi.x) + fabsf(m5 - vhi.y)
                    + fabsf(m6 - vhi.z) + fabsf(m7 - vhi.w);
            accp += exp2f(-d);                     // M pre-scaled by log2e
        }
    };

    // ---- rounds 1..3: loads(quarter qr) || pairs(quarter qp, ready) ----
    #pragma unroll
    for (int rd = 1; rd < 4; ++rd) {
        int qr = (ic + rd) & 3;                   // quarter this round computes
        int qp = (ic + rd - 1) & 3;               // quarter pairs consumes
        const float* pa = x + (qr * 128 + w * 16 + r) * IN_ + q * 8;
        const float* sj = s + (qp * 128 + win * 32) * SROW;

        load8(pa, 0);                             // issue K-half 0
        pairs16(sj);                              // VALU fills load latency
        f32x4 acc = {0.f, 0.f, 0.f, 0.f};
        mfma8(acc, 0);
        load8(pa, 8);                             // issue K-half 1
        pairs16(sj);
        mfma8(acc, 8);
        writeRows(acc, qr * 128 + w * 16);
        __syncthreads();
    }

    // ---- final pairs pass (quarter (ic+3)&3) ----
    {
        int qp = (ic + 3) & 3;
        const float* sj = s + (qp * 128 + win * 32) * SROW;
        pairs16(sj);
        pairs16(sj);
    }

    s2[win][il] = accp;
    __syncthreads();

    // exclusive final store: this block owns (o, i) for i in [ic*128, +128)
    if (t < 128) {
        float v = s2[0][t] + s2[1][t] + s2[2][t] + s2[3][t];
        out[(ic * 128 + t) * ROW_ + IN_ + o] = v;
    }
}

extern "C" void kernel_launch(void* const* d_in, const int* in_sizes, int n_in,
                              void* d_out, int out_size, void* d_ws, size_t ws_size,
                              hipStream_t stream) {
    const float* x = (const float*)d_in[0];   // [512, 512]
    const float* T = (const float*)d_in[1];   // [512, 64, 8]
    float* out = (float*)d_out;               // [512, 576]
    (void)d_ws; (void)ws_size;                // workspace unused (fill is unconditional)

    fused_kernel<<<256, 512, 0, stream>>>(x, T, out);
}